// Round 1
// baseline (180.526 us; speedup 1.0000x reference)
//
#include <hip/hip_runtime.h>
#include <cstddef>

// DCT-II matrix (float32 cast of numpy's float64 values)
static constexpr float D8[8][8] = {
  { 0.35355339059327373f, 0.35355339059327373f, 0.35355339059327373f, 0.35355339059327373f,
    0.35355339059327373f, 0.35355339059327373f, 0.35355339059327373f, 0.35355339059327373f},
  { 0.4903926402016152f,  0.4157348061512726f,  0.27778511650980114f, 0.09754516100806417f,
   -0.09754516100806417f,-0.27778511650980114f,-0.4157348061512726f, -0.4903926402016152f},
  { 0.46193976625564337f, 0.19134171618254492f,-0.19134171618254492f,-0.46193976625564337f,
   -0.46193976625564337f,-0.19134171618254492f, 0.19134171618254492f, 0.46193976625564337f},
  { 0.4157348061512726f, -0.09754516100806417f,-0.4903926402016152f, -0.27778511650980114f,
    0.27778511650980114f, 0.4903926402016152f,  0.09754516100806417f,-0.4157348061512726f},
  { 0.35355339059327373f,-0.35355339059327373f,-0.35355339059327373f, 0.35355339059327373f,
    0.35355339059327373f,-0.35355339059327373f,-0.35355339059327373f, 0.35355339059327373f},
  { 0.27778511650980114f,-0.4903926402016152f,  0.09754516100806417f, 0.4157348061512726f,
   -0.4157348061512726f, -0.09754516100806417f, 0.4903926402016152f, -0.27778511650980114f},
  { 0.19134171618254492f,-0.46193976625564337f, 0.46193976625564337f,-0.19134171618254492f,
   -0.19134171618254492f, 0.46193976625564337f,-0.46193976625564337f, 0.19134171618254492f},
  { 0.09754516100806417f,-0.27778511650980114f, 0.4157348061512726f, -0.4903926402016152f,
    0.4903926402016152f, -0.4157348061512726f,  0.27778511650980114f,-0.09754516100806417f},
};

// Quality-95 quant tables: q = clamp(floor((base*10+50)/100), 1, 255)
static constexpr float QLt[8][8] = {
  {2,1,1,2,2,4,5,6},
  {1,1,1,2,3,6,6,6},
  {1,1,2,2,4,6,7,6},
  {1,2,2,3,5,9,8,6},
  {2,2,4,6,7,11,10,8},
  {2,4,6,6,8,10,11,9},
  {5,6,8,9,10,12,12,10},
  {7,9,10,10,11,10,10,10},
};
static constexpr float QCt[8][8] = {
  {2,2,2,5,10,10,10,10},
  {2,2,3,7,10,10,10,10},
  {2,3,6,10,10,10,10,10},
  {5,7,10,10,10,10,10,10},
  {10,10,10,10,10,10,10,10},
  {10,10,10,10,10,10,10,10},
  {10,10,10,10,10,10,10,10},
  {10,10,10,10,10,10,10,10},
};

// u[k] = sum_j D8[k][j] * x[j]   (contract with D's 2nd index)
__device__ __forceinline__ void dct8(const float x[8], float u[8]) {
  #pragma unroll
  for (int k = 0; k < 8; ++k) {
    float a = D8[k][0] * x[0];
    #pragma unroll
    for (int j = 1; j < 8; ++j) a += D8[k][j] * x[j];
    u[k] = a;
  }
}

// u[j] = sum_m x[m] * D8[m][j]   (contract with D's 1st index)
__device__ __forceinline__ void idct8(const float x[8], float u[8]) {
  #pragma unroll
  for (int j = 0; j < 8; ++j) {
    float a = x[0] * D8[0][j];
    #pragma unroll
    for (int m = 1; m < 8; ++m) a += x[m] * D8[m][j];
    u[j] = a;
  }
}

// Tile: 16 rows x 128 cols per block. Grid (W/128=4, H/16=32, B=32), 256 thr.
__global__ __launch_bounds__(256) void jpeg_rt(const float* __restrict__ in,
                                               float* __restrict__ out)
{
  // Row strides padded (132, 68, 72) to keep b128 16B-aligned and bank
  // aliasing <= 2-way (free on gfx950, m136).
  __shared__ __align__(16) float Yp[16][132];
  __shared__ __align__(16) float Cbp[8][68];
  __shared__ __align__(16) float Crp[8][68];
  __shared__ __align__(16) float S1[32][72];
  __shared__ __align__(16) float S2[32][72];

  const int t   = threadIdx.x;
  const int tx  = blockIdx.x;   // 0..3
  const int ty  = blockIdx.y;   // 0..31
  const int img = blockIdx.z;   // 0..31

  const int pr = t >> 5;        // patch row 0..7   (pixel rows 2pr, 2pr+1)
  const int pc = t & 31;        // patch col 0..31  (pixel cols 4pc..4pc+3)

  const float c255 = (float)(1.0/255.0);  // matches jnp's f32 divisor

  // ---------------- stage 1: load 2x4 patch, color convert, plane writes
  {
    float yv[2][4];
    float cbv[2][4], crv[2][4];
    #pragma unroll
    for (int rr = 0; rr < 2; ++rr) {
      const size_t grow = (size_t)img * 512 + (size_t)(ty*16 + 2*pr + rr);
      const float* rp = in + (grow*512 + (size_t)(tx*128 + 4*pc))*3;
      float4 A = ((const float4*)rp)[0];
      float4 Bq = ((const float4*)rp)[1];
      float4 Cq = ((const float4*)rp)[2];
      float px[12] = {A.x,A.y,A.z,A.w,Bq.x,Bq.y,Bq.z,Bq.w,Cq.x,Cq.y,Cq.z,Cq.w};
      #pragma unroll
      for (int p = 0; p < 4; ++p) {
        float r = fminf(fmaxf(floorf(px[3*p+0]/c255), 0.0f), 255.0f);
        float g = fminf(fmaxf(floorf(px[3*p+1]/c255), 0.0f), 255.0f);
        float b = fminf(fmaxf(floorf(px[3*p+2]/c255), 0.0f), 255.0f);
        float y  =  0.299f*r + 0.587f*g + 0.114f*b;
        float cb = -0.168736f*r - 0.331264f*g + 0.5f*b + 128.0f;
        float cr =  0.5f*r - 0.418688f*g - 0.081312f*b + 128.0f;
        yv[rr][p]  = y - 128.0f;
        cbv[rr][p] = cb;
        crv[rr][p] = cr;
      }
    }
    *(float4*)&Yp[2*pr+0][4*pc] = make_float4(yv[0][0],yv[0][1],yv[0][2],yv[0][3]);
    *(float4*)&Yp[2*pr+1][4*pc] = make_float4(yv[1][0],yv[1][1],yv[1][2],yv[1][3]);
    float cb0 = ((cbv[0][0]+cbv[0][1]) + (cbv[1][0]+cbv[1][1]))*0.25f - 128.0f;
    float cb1 = ((cbv[0][2]+cbv[0][3]) + (cbv[1][2]+cbv[1][3]))*0.25f - 128.0f;
    float cr0 = ((crv[0][0]+crv[0][1]) + (crv[1][0]+crv[1][1]))*0.25f - 128.0f;
    float cr1 = ((crv[0][2]+crv[0][3]) + (crv[1][2]+crv[1][3]))*0.25f - 128.0f;
    *(float2*)&Cbp[pr][2*pc] = make_float2(cb0, cb1);
    *(float2*)&Crp[pr][2*pc] = make_float2(cr0, cr1);
  }
  __syncthreads();

  // ---------------- luma pass A: row DCT (t1 = X * D^T), rows -> S1
  {
    const int b = t >> 3, i = t & 7;
    const int br = b >> 4, bc = b & 15;
    const float* src = &Yp[br*8 + i][bc*8];
    float xr[8], u[8];
    *(float4*)&xr[0] = *(const float4*)&src[0];
    *(float4*)&xr[4] = *(const float4*)&src[4];
    dct8(xr, u);
    *(float4*)&S1[b][i*8+0] = make_float4(u[0],u[1],u[2],u[3]);
    *(float4*)&S1[b][i*8+4] = make_float4(u[4],u[5],u[6],u[7]);
  }
  __syncthreads();

  // ---------------- luma pass B+C: col DCT + quant + row IDCT, rows -> S2
  {
    const int b = t >> 3, kk = t & 7;  // kk = coefficient column l
    float s[8], u[8], v[8];
    #pragma unroll
    for (int i = 0; i < 8; ++i) s[i] = S1[b][i*8 + kk];  // 2-way bank alias only
    dct8(s, u);                 // u[m] = coef[m][kk]
    #pragma unroll
    for (int m = 0; m < 8; ++m) {
      float qv = QLt[m][kk];
      u[m] = rintf(u[m]/qv) * qv;
    }
    idct8(u, v);                // v[j] = (deq^T * D)[kk][j]
    *(float4*)&S2[b][kk*8+0] = make_float4(v[0],v[1],v[2],v[3]);
    *(float4*)&S2[b][kk*8+4] = make_float4(v[4],v[5],v[6],v[7]);
  }
  __syncthreads();

  // ---------------- luma pass D: col IDCT, rec rows back into Yp
  {
    const int b = t >> 3, j = t & 7;
    float w[8], z[8];
    #pragma unroll
    for (int m = 0; m < 8; ++m) w[m] = S2[b][m*8 + j];
    idct8(w, z);                // z[i] = rec[j][i]
    const int br = b >> 4, bc = b & 15;
    *(float4*)&Yp[br*8 + j][bc*8 + 0] = make_float4(z[0],z[1],z[2],z[3]);
    *(float4*)&Yp[br*8 + j][bc*8 + 4] = make_float4(z[4],z[5],z[6],z[7]);
  }
  // ---------------- chroma pass A (same phase: S1 free, planes stable)
  if (t < 128) {
    const int b = t >> 3, i = t & 7;          // b: 0..7 Cb, 8..15 Cr
    const float* plane = (b & 8) ? &Crp[0][0] : &Cbp[0][0];
    const float* src = plane + i*68 + (b & 7)*8;
    float xr[8], u[8];
    *(float4*)&xr[0] = *(const float4*)&src[0];
    *(float4*)&xr[4] = *(const float4*)&src[4];
    dct8(xr, u);
    *(float4*)&S1[b][i*8+0] = make_float4(u[0],u[1],u[2],u[3]);
    *(float4*)&S1[b][i*8+4] = make_float4(u[4],u[5],u[6],u[7]);
  }
  __syncthreads();

  // ---------------- chroma pass B+C
  if (t < 128) {
    const int b = t >> 3, kk = t & 7;
    float s[8], u[8], v[8];
    #pragma unroll
    for (int i = 0; i < 8; ++i) s[i] = S1[b][i*8 + kk];
    dct8(s, u);
    #pragma unroll
    for (int m = 0; m < 8; ++m) {
      float qv = QCt[m][kk];
      u[m] = rintf(u[m]/qv) * qv;
    }
    idct8(u, v);
    *(float4*)&S2[b][kk*8+0] = make_float4(v[0],v[1],v[2],v[3]);
    *(float4*)&S2[b][kk*8+4] = make_float4(v[4],v[5],v[6],v[7]);
  }
  __syncthreads();

  // ---------------- chroma pass D: rec rows back into Cb/Cr planes
  if (t < 128) {
    const int b = t >> 3, j = t & 7;
    float w[8], z[8];
    #pragma unroll
    for (int m = 0; m < 8; ++m) w[m] = S2[b][m*8 + j];
    idct8(w, z);
    float* plane = (b & 8) ? &Crp[0][0] : &Cbp[0][0];
    float* dst = plane + j*68 + (b & 7)*8;
    *(float4*)&dst[0] = make_float4(z[0],z[1],z[2],z[3]);
    *(float4*)&dst[4] = make_float4(z[4],z[5],z[6],z[7]);
  }
  __syncthreads();

  // ---------------- output: upsample chroma, YCbCr->RGB, round/clip, /255
  {
    float y0[4], y1[4];
    *(float4*)y0 = *(const float4*)&Yp[2*pr+0][4*pc];
    *(float4*)y1 = *(const float4*)&Yp[2*pr+1][4*pc];
    float2 cbp2 = *(const float2*)&Cbp[pr][2*pc];
    float2 crp2 = *(const float2*)&Crp[pr][2*pc];
    float cbq[2] = {cbp2.x, cbp2.y};
    float crq[2] = {crp2.x, crp2.y};
    #pragma unroll
    for (int rr = 0; rr < 2; ++rr) {
      float ov[12];
      #pragma unroll
      for (int p = 0; p < 4; ++p) {
        float y2  = (rr ? y1[p] : y0[p]) + 128.0f;
        float cb2 = cbq[p>>1] + 128.0f;
        float cr2 = crq[p>>1] + 128.0f;
        float r2 = y2 + 1.402f*(cr2 - 128.0f);
        float g2 = y2 - 0.344136f*(cb2 - 128.0f) - 0.714136f*(cr2 - 128.0f);
        float b2 = y2 + 1.772f*(cb2 - 128.0f);
        ov[3*p+0] = rintf(fminf(fmaxf(r2, 0.0f), 255.0f)) / 255.0f;
        ov[3*p+1] = rintf(fminf(fmaxf(g2, 0.0f), 255.0f)) / 255.0f;
        ov[3*p+2] = rintf(fminf(fmaxf(b2, 0.0f), 255.0f)) / 255.0f;
      }
      const size_t grow = (size_t)img * 512 + (size_t)(ty*16 + 2*pr + rr);
      float* op = out + (grow*512 + (size_t)(tx*128 + 4*pc))*3;
      ((float4*)op)[0] = make_float4(ov[0],ov[1],ov[2],ov[3]);
      ((float4*)op)[1] = make_float4(ov[4],ov[5],ov[6],ov[7]);
      ((float4*)op)[2] = make_float4(ov[8],ov[9],ov[10],ov[11]);
    }
  }
}

extern "C" void kernel_launch(void* const* d_in, const int* in_sizes, int n_in,
                              void* d_out, int out_size, void* d_ws, size_t ws_size,
                              hipStream_t stream) {
  (void)in_sizes; (void)n_in; (void)d_ws; (void)ws_size; (void)out_size;
  const float* x = (const float*)d_in[0];
  float* out = (float*)d_out;
  dim3 grid(4, 32, 32);   // W/128, H/16, B
  jpeg_rt<<<grid, dim3(256), 0, stream>>>(x, out);
}